// Round 6
// baseline (185.391 us; speedup 1.0000x reference)
//
#include <hip/hip_runtime.h>
#include <hip/hip_cooperative_groups.h>
#include <cstdint>
#include <cstddef>

// DotProductAttention: O = softmax_q(QK^T/8 + log(mask)) @ V
// P = mask * exp(QK^T/8); L[b,k] = sum_q P; O = P @ (diag(1/L) V).
// R8: single cooperative kernel (4 phases, 3 grid.sync) — R7 post-mortem found
// ~60us (1/3 of wall time) was inter-dispatch gap. Grid 1024 = 4 blocks/CU
// exactly (36KB LDS union, launch_bounds(256,4)). Host pre-checks occupancy
// and falls back to 4 normal phase-masked launches if coop is unavailable.
// Stats restructured to (qt x kt) tiles with b-loop INSIDE: the batch-invariant
// mask tile lives in 16 registers/lane for the whole phase (mask L3 traffic
// 268MB -> 17MB); per-b colsums accumulate in LDS (ds_add_f32), one global
// atomic flush per block. cast/vtrans/attn bodies verbatim from R7 (verified).

#define LSEQ 2048
#define DHEAD 64

typedef __bf16 v8bf __attribute__((ext_vector_type(8)));
typedef __bf16 v4bf __attribute__((ext_vector_type(4)));
typedef float v4f __attribute__((ext_vector_type(4)));

#define MFMA16(a, b, c) __builtin_amdgcn_mfma_f32_16x16x32_bf16(a, b, c, 0, 0, 0)

__device__ __forceinline__ void gl_lds16(const void* g, void* l) {
  __builtin_amdgcn_global_load_lds(
      (__attribute__((address_space(1))) void*)g,
      (__attribute__((address_space(3))) void*)l, 16, 0, 0);
}

struct StatsS {  // 36864 B
  __bf16 Qt[2][64 * 64];
  __bf16 Kt[2][64 * 64];
  float Lacc[16][64];
};
struct AttnS {  // 32768 B
  __bf16 Kt[64 * 64];
  __bf16 Vt[64 * 64];
  __bf16 Pt[128 * 64];  // 16B-unit XOR swizzled (R7-verified)
};
struct VtrS {  // 8448 B
  float tile[32][65];
  float invl[32];
};

// phases bitmask: 1=cast 2=stats 4=vtrans 8=attn 16=do grid.sync (coop mode)
__global__ __launch_bounds__(256, 4) void fused_k(
    const float* __restrict__ Q, const float* __restrict__ K,
    const float* __restrict__ V, const float* __restrict__ mask,
    __bf16* __restrict__ Qb, __bf16* __restrict__ Kb, __bf16* __restrict__ Vts,
    float* __restrict__ Lsum, float* __restrict__ out, int phases) {
  __shared__ __align__(16) union {
    StatsS s;
    AttnS a;
    VtrS t;
  } sm;
  const int bx = blockIdx.x;
  const int tid = threadIdx.x;
  const int w = tid >> 6, lane = tid & 63;
  const int quad = lane >> 4, n = lane & 15;

  // ---- phase 0: cast Q(x0.125)/K -> bf16, zero out and Lsum ----------------
  if (phases & 1) {
#pragma unroll
    for (int rep = 0; rep < 2; ++rep) {
      size_t j = (size_t)(bx * 2 + rep) * 256 + tid;  // 0..524287
      size_t i = j * 4;
      float4 q = *(const float4*)(Q + i);
      float4 k = *(const float4*)(K + i);
      v4bf qo = {(__bf16)(q.x * 0.125f), (__bf16)(q.y * 0.125f),
                 (__bf16)(q.z * 0.125f), (__bf16)(q.w * 0.125f)};
      v4bf ko = {(__bf16)k.x, (__bf16)k.y, (__bf16)k.z, (__bf16)k.w};
      *(v4bf*)(Qb + i) = qo;
      *(v4bf*)(Kb + i) = ko;
      float4 z = {0.f, 0.f, 0.f, 0.f};
      *(float4*)(out + i) = z;  // out is exactly 16*2048*64 floats = Q's count
    }
    if (bx < 128) Lsum[bx * 256 + tid] = 0.f;  // 32768 floats
  }
  if (phases & 16) cooperative_groups::this_grid().sync();

  // ---- phase 1: stats. Block owns (qt,kt) 64x64 tile; b-loop inside. -------
  // Natural orientation (R2-verified): A=Q rows w*16+n, B=K rows sub*16+n,
  // C row(q)=quad*4+r col(k')=n. Mask tile hoisted to 16 regs (b-invariant).
  if (phases & 2) {
    auto& S = sm.s;
    const int qt = bx >> 5, kt = bx & 31;
    const int q0 = qt * 64, k0 = kt * 64;
#pragma unroll
    for (int t = 0; t < 4; ++t) ((float*)S.Lacc)[t * 256 + tid] = 0.f;
    float msk[4][4];
#pragma unroll
    for (int sub = 0; sub < 4; ++sub)
#pragma unroll
      for (int r = 0; r < 4; ++r)
        msk[sub][r] =
            mask[(size_t)(q0 + w * 16 + quad * 4 + r) * LSEQ + k0 + sub * 16 + n];

#define SSTAGE(buf, bb)                                                          \
  {                                                                              \
    _Pragma("unroll") for (int i = 0; i < 2; ++i) {                              \
      int s = (w * 2 + i) * 64 + lane;                                           \
      int row = s >> 3, gc = (s & 7) ^ (row & 7);                                \
      gl_lds16(Qb + ((size_t)(bb) * LSEQ + q0 + row) * DHEAD + gc * 8,           \
               &S.Qt[buf][s * 8]);                                               \
      gl_lds16(Kb + ((size_t)(bb) * LSEQ + k0 + row) * DHEAD + gc * 8,           \
               &S.Kt[buf][s * 8]);                                               \
    }                                                                            \
  }
    SSTAGE(0, 0);
    __syncthreads();  // covers Lacc zero + stage 0

    int cur = 0;
#pragma unroll 1
    for (int b = 0; b < 16; ++b) {
      if (b < 15) SSTAGE(cur ^ 1, b + 1);  // in flight under compute
      const int qr = w * 16 + n;
      v8bf aq0 = *(const v8bf*)&S.Qt[cur][qr * 64 + ((quad) ^ (qr & 7)) * 8];
      v8bf aq1 = *(const v8bf*)&S.Qt[cur][qr * 64 + ((4 + quad) ^ (qr & 7)) * 8];
      float red[4];
      __builtin_amdgcn_s_setprio(1);
#pragma unroll
      for (int sub = 0; sub < 4; ++sub) {
        const int kr = sub * 16 + n;
        v8bf b0 = *(const v8bf*)&S.Kt[cur][kr * 64 + ((quad) ^ (kr & 7)) * 8];
        v8bf b1 = *(const v8bf*)&S.Kt[cur][kr * 64 + ((4 + quad) ^ (kr & 7)) * 8];
        v4f c = {0.f, 0.f, 0.f, 0.f};
        c = MFMA16(aq0, b0, c);
        c = MFMA16(aq1, b1, c);
        float v = msk[sub][0] * __expf(c[0]) + msk[sub][1] * __expf(c[1]) +
                  msk[sub][2] * __expf(c[2]) + msk[sub][3] * __expf(c[3]);
        v += __shfl_xor(v, 16);  // reduce over quads (q rows)
        v += __shfl_xor(v, 32);
        red[sub] = v;
      }
      __builtin_amdgcn_s_setprio(0);
      if (quad == 0) {
#pragma unroll
        for (int sub = 0; sub < 4; ++sub)
          atomicAdd(&S.Lacc[b][sub * 16 + n], red[sub]);  // ds_add_f32
      }
      __syncthreads();  // drains stage vmcnt; orders Lacc; publishes next buf
      cur ^= 1;
    }
#undef SSTAGE
    // flush Lacc -> global Lsum (32 qt-blocks contribute per (b,k))
#pragma unroll
    for (int p = 0; p < 4; ++p) {
      int idx = p * 256 + tid;
      unsafeAtomicAdd(&Lsum[(size_t)(idx >> 6) * LSEQ + k0 + (idx & 63)],
                      ((float*)S.Lacc)[idx]);
    }
  }
  if (phases & 16) cooperative_groups::this_grid().sync();

  // ---- phase 2: Vts[b][v][k] = bf16(V[b][k][v] / L[b][k]) ------------------
  if (phases & 4) {
    auto& T = sm.t;
    const int b = bx >> 6;
    const int k0v = (bx & 63) * 32;
    if (tid < 32) T.invl[tid] = 1.0f / Lsum[(size_t)b * LSEQ + k0v + tid];
#pragma unroll
    for (int t = 0; t < 8; ++t) {
      int flat = t * 256 + tid;
      int k = flat >> 6, v = flat & 63;
      T.tile[k][v] = V[((size_t)b * LSEQ + k0v + k) * DHEAD + v];
    }
    __syncthreads();
#pragma unroll
    for (int t = 0; t < 8; ++t) {
      int flat = t * 256 + tid;
      int v = flat >> 5, k = flat & 31;
      Vts[((size_t)b * DHEAD + v) * LSEQ + k0v + k] = (__bf16)(T.tile[k][v] * T.invl[k]);
    }
  }
  if (phases & 16) cooperative_groups::this_grid().sync();

  // ---- phase 3: attn (R7 body verbatim): split-phase single-buf pipeline ---
  if (phases & 8) {
    auto& A = sm.a;
    const int b = bx >> 6;
    const int kc = (bx >> 4) & 3;
    const int q0 = (bx & 15) * 128;

#define ASTAGE_K(kb2)                                                            \
  {                                                                              \
    _Pragma("unroll") for (int i = 0; i < 2; ++i) {                              \
      int s = (w * 2 + i) * 64 + lane;                                           \
      int row = s >> 3, gc = (s & 7) ^ (row & 7);                                \
      gl_lds16(Kb + ((size_t)b * LSEQ + (kb2) + row) * DHEAD + gc * 8,           \
               &A.Kt[s * 8]);                                                    \
    }                                                                            \
  }
#define ASTAGE_V(kb2)                                                            \
  {                                                                              \
    _Pragma("unroll") for (int i = 0; i < 2; ++i) {                              \
      int s = (w * 2 + i) * 64 + lane;                                           \
      int row = s >> 3, gc = (s & 7) ^ (row & 7);                                \
      gl_lds16(Vts + ((size_t)b * DHEAD + row) * LSEQ + (kb2) + gc * 8,          \
               &A.Vt[s * 8]);                                                    \
    }                                                                            \
  }

    const int qg0 = q0 + w * 32 + n;  // q-half 0; half 1 = qg0 + 16

    v8bf bq[2][2];
#pragma unroll
    for (int h = 0; h < 2; ++h)
#pragma unroll
      for (int dh = 0; dh < 2; ++dh)
        bq[h][dh] = *(const v8bf*)(Qb + ((size_t)b * LSEQ + qg0 + h * 16) * DHEAD +
                                   dh * 32 + quad * 8);

    v4f acc[2][4];
#pragma unroll
    for (int h = 0; h < 2; ++h)
#pragma unroll
      for (int vs = 0; vs < 4; ++vs) acc[h][vs] = (v4f){0.f, 0.f, 0.f, 0.f};

    const int kbeg = kc * 512;
    ASTAGE_K(kbeg);
    ASTAGE_V(kbeg);
    __syncthreads();

#pragma unroll 1
    for (int ks = 0; ks < 8; ++ks) {
      const int kb = kbeg + ks * 64;
      v4f m4[2][4];
#pragma unroll
      for (int h = 0; h < 2; ++h)
#pragma unroll
        for (int sub = 0; sub < 4; ++sub)
          m4[h][sub] = *(const v4f*)(mask + (size_t)(qg0 + h * 16) * LSEQ + kb +
                                     sub * 16 + quad * 4);

      // QK^T swapped: S[k'][q] both halves; P -> Pt (swizzled v4bf, own rows)
      __builtin_amdgcn_s_setprio(1);
#pragma unroll
      for (int sub = 0; sub < 4; ++sub) {
        const int kr = sub * 16 + n;
        v8bf a0 = *(const v8bf*)&A.Kt[kr * 64 + ((quad) ^ (kr & 7)) * 8];
        v8bf a1 = *(const v8bf*)&A.Kt[kr * 64 + ((4 + quad) ^ (kr & 7)) * 8];
#pragma unroll
        for (int h = 0; h < 2; ++h) {
          v4f c = {0.f, 0.f, 0.f, 0.f};
          c = MFMA16(a0, bq[h][0], c);
          c = MFMA16(a1, bq[h][1], c);
          v4bf pv;
#pragma unroll
          for (int r = 0; r < 4; ++r) pv[r] = (__bf16)(m4[h][sub][r] * __expf(c[r]));
          const int prow = w * 32 + h * 16 + n;
          *(v4bf*)((char*)A.Pt + prow * 128 +
                   (((sub * 2 + (quad >> 1)) ^ (n & 7)) << 4) + ((quad & 1) << 3)) = pv;
        }
      }
      __builtin_amdgcn_s_setprio(0);
      __syncthreads();  // barrier1: Kt free; Pt published
      if (ks < 7) ASTAGE_K(kb + 64);  // overlaps PV

      __builtin_amdgcn_s_setprio(1);
#pragma unroll
      for (int kk = 0; kk < 2; ++kk) {
        const int pr0 = w * 32 + n, pr1 = pr0 + 16;
        v8bf ap0 =
            *(const v8bf*)((char*)A.Pt + pr0 * 128 + (((kk * 4 + quad) ^ (n & 7)) << 4));
        v8bf ap1 =
            *(const v8bf*)((char*)A.Pt + pr1 * 128 + (((kk * 4 + quad) ^ (n & 7)) << 4));
#pragma unroll
        for (int vs = 0; vs < 4; ++vs) {
          const int vr = vs * 16 + n;
          v8bf bv = *(const v8bf*)&A.Vt[vr * 64 + ((kk * 4 + quad) ^ (vr & 7)) * 8];
          acc[0][vs] = MFMA16(ap0, bv, acc[0][vs]);
          acc[1][vs] = MFMA16(ap1, bv, acc[1][vs]);
        }
      }
      __builtin_amdgcn_s_setprio(0);
      __syncthreads();  // barrier2: Vt free; Kt(ks+1) drained
      if (ks < 7) ASTAGE_V(kb + 64);  // overlaps next QK
    }
#undef ASTAGE_K
#undef ASTAGE_V

#pragma unroll
    for (int h = 0; h < 2; ++h)
#pragma unroll
      for (int vs = 0; vs < 4; ++vs)
#pragma unroll
        for (int r = 0; r < 4; ++r)
          unsafeAtomicAdd(&out[((size_t)b * LSEQ + q0 + w * 32 + h * 16 + quad * 4 + r) *
                                   DHEAD +
                               vs * 16 + n],
                          acc[h][vs][r]);
  }
}

extern "C" void kernel_launch(void* const* d_in, const int* in_sizes, int n_in,
                              void* d_out, int out_size, void* d_ws, size_t ws_size,
                              hipStream_t stream) {
  const float* Q = (const float*)d_in[0];
  const float* K = (const float*)d_in[1];
  const float* V = (const float*)d_in[2];
  const float* mask = (const float*)d_in[3];
  float* out = (float*)d_out;

  char* ws = (char*)d_ws;
  // ws: Qb 4MiB | Kb 4MiB | Vts 4MiB | Lsum 128KiB  (12.13 MiB)
  __bf16* Qb = (__bf16*)(ws);
  __bf16* Kb = (__bf16*)(ws + (4 << 20));
  __bf16* Vts = (__bf16*)(ws + (8 << 20));
  float* Lsum = (float*)(ws + (12 << 20));
  const size_t need = ((size_t)12 << 20) + (1 << 17);
  if (ws_size < need) return;  // workspace too small — fail loudly (poison out)

  int nb = 0;
  hipOccupancyMaxActiveBlocksPerMultiprocessor(&nb, fused_k, 256, 0);
  if (nb >= 4) {
    int phases = 31;  // all phases + grid syncs
    void* args[] = {(void*)&Q,  (void*)&K,    (void*)&V,    (void*)&mask,
                    (void*)&Qb, (void*)&Kb,   (void*)&Vts,  (void*)&Lsum,
                    (void*)&out, (void*)&phases};
    hipError_t e = hipLaunchCooperativeKernel(fused_k, dim3(1024), dim3(256), args,
                                              (unsigned)0, stream);
    if (e == hipSuccess) return;
  }
  // Fallback: 4 normal launches; stream ordering replaces grid.sync (bit 16 off)
  fused_k<<<1024, 256, 0, stream>>>(Q, K, V, mask, Qb, Kb, Vts, Lsum, out, 1);
  fused_k<<<1024, 256, 0, stream>>>(Q, K, V, mask, Qb, Kb, Vts, Lsum, out, 2);
  fused_k<<<1024, 256, 0, stream>>>(Q, K, V, mask, Qb, Kb, Vts, Lsum, out, 4);
  fused_k<<<1024, 256, 0, stream>>>(Q, K, V, mask, Qb, Kb, Vts, Lsum, out, 8);
}